// Round 1
// baseline (566.275 us; speedup 1.0000x reference)
//
#include <hip/hip_runtime.h>
#include <hip/hip_bf16.h>

// Problem constants (from reference setup_inputs)
#define BSZ      8
#define NOBJ     10000
#define NATTR    2000
#define IN_DIM   256
#define OUT_DIM  256
#define ATTR_DIM 128
#define E_NUM    800000
#define M_ROWS   (BSZ * NOBJ)    // 80000 object rows
#define K_TOT    (IN_DIM + ATTR_DIM)  // 384 fused K

typedef short bf16x8 __attribute__((ext_vector_type(8)));
typedef float f32x4  __attribute__((ext_vector_type(4)));

__device__ __forceinline__ short f2bf(float f) {
    union { float f; unsigned u; } v; v.f = f;
    unsigned r = v.u + 0x7FFFu + ((v.u >> 16) & 1u);  // RNE
    return (short)(r >> 16);
}

// ---------------- prep: fused weight precompute ----------------
// M1[n][c] = sum_k W_upd[n][256+k] * W_proj[k][c]   (W2 @ W_proj, 256x256)
__global__ void prep1(const float* __restrict__ W_upd, const float* __restrict__ W_proj,
                      float* __restrict__ M1) {
    int i = blockIdx.x;   // output row n
    int j = threadIdx.x;  // output col c
    const float* wrow = W_upd + i * 512 + 256;
    float acc = 0.f;
    for (int k = 0; k < 256; ++k) acc += wrow[k] * W_proj[k * 256 + j];
    M1[i * 256 + j] = acc;
}

// Wbig[n][0:256] = bf16(W1[n][:]); Wbig[n][256:384] = bf16((M1 @ W_a2o)[n][:])
// v1[n] = M1[n][:] . b_a2o ; v2[n] = W2[n][:] . b_proj + b_upd[n]
__global__ void prep2(const float* __restrict__ W_upd, const float* __restrict__ W_a2o,
                      const float* __restrict__ b_a2o, const float* __restrict__ b_proj,
                      const float* __restrict__ b_upd, const float* __restrict__ M1,
                      unsigned short* __restrict__ Wbig, float* __restrict__ v1,
                      float* __restrict__ v2) {
    int i = blockIdx.x;   // n
    int j = threadIdx.x;  // 0..127
    const float* m1row = M1 + i * 256;
    float acc = 0.f;
    for (int k = 0; k < 256; ++k) acc += m1row[k] * W_a2o[k * 128 + j];
    Wbig[i * K_TOT + 256 + j] = (unsigned short)f2bf(acc);
    Wbig[i * K_TOT + j]       = (unsigned short)f2bf(W_upd[i * 512 + j]);
    Wbig[i * K_TOT + 128 + j] = (unsigned short)f2bf(W_upd[i * 512 + 128 + j]);

    __shared__ float r1[128], r2[128];
    r1[j] = m1row[j] * b_a2o[j] + m1row[j + 128] * b_a2o[j + 128];
    r2[j] = W_upd[i * 512 + 256 + j] * b_proj[j] +
            W_upd[i * 512 + 256 + 128 + j] * b_proj[j + 128];
    __syncthreads();
    for (int s = 64; s > 0; s >>= 1) {
        if (j < s) { r1[j] += r1[j + s]; r2[j] += r2[j + s]; }
        __syncthreads();
    }
    if (j == 0) { v1[i] = r1[0]; v2[i] = r2[0] + b_upd[i]; }
}

// ---------------- edge counting sort ----------------
__global__ void hist_kernel(const int* __restrict__ ei, int* __restrict__ count) {
    int e = blockIdx.x * blockDim.x + threadIdx.x;
    if (e < E_NUM) atomicAdd(&count[ei[e]], 1);
}

// single-block exclusive scan of count[80000] -> start[80001], cursor copy
__global__ void scan_kernel(const int* __restrict__ count, int* __restrict__ start,
                            int* __restrict__ cursor) {
    const int CH = 80;  // 1024*80 >= 80000
    int t = threadIdx.x;
    int lo = t * CH, hi = min(lo + CH, M_ROWS);
    int sum = 0;
    for (int i = lo; i < hi; ++i) sum += count[i];
    __shared__ int part[1024];
    part[t] = sum;
    __syncthreads();
    for (int off = 1; off < 1024; off <<= 1) {
        int v = (t >= off) ? part[t - off] : 0;
        __syncthreads();
        part[t] += v;
        __syncthreads();
    }
    int run = (t == 0) ? 0 : part[t - 1];
    for (int i = lo; i < hi; ++i) {
        start[i] = run; cursor[i] = run; run += count[i];
    }
    if (t == 1023) start[M_ROWS] = E_NUM;
}

__global__ void scatter_kernel(const int* __restrict__ ei, const float* __restrict__ ew,
                               int* __restrict__ cursor, int* __restrict__ s_attr,
                               float* __restrict__ s_w) {
    int e = blockIdx.x * blockDim.x + threadIdx.x;
    if (e < E_NUM) {
        int o = ei[e];
        int pos = atomicAdd(&cursor[o], 1);
        s_attr[pos] = ei[E_NUM + e];
        s_w[pos] = ew[e];
    }
}

// ---------------- aggregation: one wave per object, no atomics ----------------
__global__ void __launch_bounds__(256) agg_kernel(const float* __restrict__ attrs,
        const int* __restrict__ start, const int* __restrict__ s_attr,
        const float* __restrict__ s_w, float* __restrict__ nrm, float* __restrict__ s_out) {
    int wave = (int)((blockIdx.x * blockDim.x + threadIdx.x) >> 6);
    int lane = threadIdx.x & 63;
    if (wave >= M_ROWS) return;
    int beg = start[wave], end = start[wave + 1];
    float a0 = 0.f, a1 = 0.f, ws = 0.f;
    for (int j = beg; j < end; ++j) {
        int a = s_attr[j];
        float w = s_w[j];
        float2 v = *reinterpret_cast<const float2*>(attrs + (size_t)a * ATTR_DIM + lane * 2);
        a0 += w * v.x; a1 += w * v.y; ws += w;
    }
    float inv = 1.f / fmaxf(ws, 1e-6f);
    float2 o; o.x = a0 * inv; o.y = a1 * inv;
    *reinterpret_cast<float2*>(nrm + (size_t)wave * ATTR_DIM + lane * 2) = o;
    if (lane == 0) s_out[wave] = ws * inv;
}

// ---------------- fused output GEMM: out = relu(X[80000,384] @ Wbig.T + s*v1 + v2) ----------------
// block = 256 thr = 4 waves; wave computes 32 rows x 256 cols; block = 128 rows. grid = 625.
__global__ void __launch_bounds__(256, 2) gemm_out(
    const float* __restrict__ obj, const float* __restrict__ nrm,
    const unsigned short* __restrict__ Wbig, const float* __restrict__ v1,
    const float* __restrict__ v2, const float* __restrict__ s_arr,
    float* __restrict__ out) {
    __shared__ unsigned short Bs[256][40];  // 32 used + 8 pad (bank spread), rows 16B-aligned

    int tid = threadIdx.x;
    int w = tid >> 6, lane = tid & 63;
    int l15 = lane & 15, quad = lane >> 4;
    int m_base = blockIdx.x * 128 + w * 32;

    f32x4 acc[2][16];
#pragma unroll
    for (int a = 0; a < 2; ++a)
#pragma unroll
        for (int b = 0; b < 16; ++b) acc[a][b] = (f32x4){0.f, 0.f, 0.f, 0.f};

    for (int kt = 0; kt < 12; ++kt) {
        int k0 = kt * 32;
        __syncthreads();
        {   // stage B chunk: thread t loads Wbig[t][k0..k0+32)
            const int4* src = reinterpret_cast<const int4*>(Wbig + tid * K_TOT + k0);
            int4 q0 = src[0], q1 = src[1], q2 = src[2], q3 = src[3];
            int4* dst = reinterpret_cast<int4*>(&Bs[tid][0]);
            dst[0] = q0; dst[1] = q1; dst[2] = q2; dst[3] = q3;
        }
        __syncthreads();

        bf16x8 af[2];
#pragma unroll
        for (int mt = 0; mt < 2; ++mt) {
            int m = m_base + mt * 16 + l15;
            const float* p;
            if (k0 < 256) p = obj + (size_t)m * 256 + k0 + quad * 8;
            else          p = nrm + (size_t)m * 128 + (k0 - 256) + quad * 8;
            float4 x0 = *reinterpret_cast<const float4*>(p);
            float4 x1 = *reinterpret_cast<const float4*>(p + 4);
            bf16x8 a;
            a[0] = f2bf(x0.x); a[1] = f2bf(x0.y); a[2] = f2bf(x0.z); a[3] = f2bf(x0.w);
            a[4] = f2bf(x1.x); a[5] = f2bf(x1.y); a[6] = f2bf(x1.z); a[7] = f2bf(x1.w);
            af[mt] = a;
        }
#pragma unroll
        for (int nt = 0; nt < 16; ++nt) {
            bf16x8 bf_ = *reinterpret_cast<const bf16x8*>(&Bs[nt * 16 + l15][quad * 8]);
            acc[0][nt] = __builtin_amdgcn_mfma_f32_16x16x32_bf16(af[0], bf_, acc[0][nt], 0, 0, 0);
            acc[1][nt] = __builtin_amdgcn_mfma_f32_16x16x32_bf16(af[1], bf_, acc[1][nt], 0, 0, 0);
        }
    }

    float v1v[16], v2v[16];
#pragma unroll
    for (int nt = 0; nt < 16; ++nt) {
        v1v[nt] = v1[nt * 16 + l15];
        v2v[nt] = v2[nt * 16 + l15];
    }
#pragma unroll
    for (int mt = 0; mt < 2; ++mt) {
#pragma unroll
        for (int r = 0; r < 4; ++r) {
            int m = m_base + mt * 16 + quad * 4 + r;
            float sv = s_arr[m];
            float* orow = out + (size_t)m * 256;
#pragma unroll
            for (int nt = 0; nt < 16; ++nt) {
                float val = acc[mt][nt][r] + sv * v1v[nt] + v2v[nt];
                orow[nt * 16 + l15] = fmaxf(val, 0.f);
            }
        }
    }
}

// ---------------- launch ----------------
extern "C" void kernel_launch(void* const* d_in, const int* in_sizes, int n_in,
                              void* d_out, int out_size, void* d_ws, size_t ws_size,
                              hipStream_t stream) {
    const float* obj    = (const float*)d_in[0];
    const float* attrs  = (const float*)d_in[1];
    const int*   ei     = (const int*)d_in[2];
    const float* ew     = (const float*)d_in[3];
    const float* W_a2o  = (const float*)d_in[4];
    const float* b_a2o  = (const float*)d_in[5];
    const float* W_proj = (const float*)d_in[6];
    const float* b_proj = (const float*)d_in[7];
    const float* W_upd  = (const float*)d_in[8];
    const float* b_upd  = (const float*)d_in[9];
    float* out = (float*)d_out;
    char* ws = (char*)d_ws;

    // workspace layout (bytes)
    float* nrm            = (float*)(ws);                       // 80000*128*4 = 40,960,000
    float* s_arr          = (float*)(ws + 40960000);            // 320,000
    int*   count          = (int*)  (ws + 41280000);            // 320,000
    int*   start          = (int*)  (ws + 41600000);            // 320,004 (pad to 320,256)
    int*   cursor         = (int*)  (ws + 41920256);            // 320,000
    int*   s_attr         = (int*)  (ws + 42240256);            // 3,200,000
    float* s_w            = (float*)(ws + 45440256);            // 3,200,000
    float* M1             = (float*)(ws + 48640256);            // 262,144
    unsigned short* Wbig  = (unsigned short*)(ws + 48902400);   // 196,608
    float* v1             = (float*)(ws + 49099008);            // 1,024
    float* v2             = (float*)(ws + 49100032);            // 1,024

    hipMemsetAsync(count, 0, M_ROWS * sizeof(int), stream);

    prep1<<<256, 256, 0, stream>>>(W_upd, W_proj, M1);
    prep2<<<256, 128, 0, stream>>>(W_upd, W_a2o, b_a2o, b_proj, b_upd, M1, Wbig, v1, v2);
    hist_kernel<<<(E_NUM + 255) / 256, 256, 0, stream>>>(ei, count);
    scan_kernel<<<1, 1024, 0, stream>>>(count, start, cursor);
    scatter_kernel<<<(E_NUM + 255) / 256, 256, 0, stream>>>(ei, ew, cursor, s_attr, s_w);
    agg_kernel<<<M_ROWS / 4, 256, 0, stream>>>(attrs, start, s_attr, s_w, nrm, s_arr);
    gemm_out<<<M_ROWS / 128, 256, 0, stream>>>(obj, nrm, Wbig, v1, v2, s_arr, out);
}

// Round 2
// 392.802 us; speedup vs baseline: 1.4416x; 1.4416x over previous
//
#include <hip/hip_runtime.h>
#include <hip/hip_bf16.h>

// Problem constants (from reference setup_inputs)
#define BSZ      8
#define NOBJ     10000
#define NATTR    2000
#define IN_DIM   256
#define OUT_DIM  256
#define ATTR_DIM 128
#define E_NUM    800000
#define M_ROWS   (BSZ * NOBJ)    // 80000 object rows
#define K_TOT    (IN_DIM + ATTR_DIM)  // 384 fused K

#define SCAN_CHUNK 1024
#define SCAN_NBLK  ((M_ROWS + SCAN_CHUNK - 1) / SCAN_CHUNK)  // 79

typedef short bf16x8 __attribute__((ext_vector_type(8)));
typedef float f32x4  __attribute__((ext_vector_type(4)));

__device__ __forceinline__ short f2bf(float f) {
    union { float f; unsigned u; } v; v.f = f;
    unsigned r = v.u + 0x7FFFu + ((v.u >> 16) & 1u);  // RNE
    return (short)(r >> 16);
}

// ---------------- prep: fused weight precompute ----------------
// M1[n][c] = sum_k W_upd[n][256+k] * W_proj[k][c]   (W2 @ W_proj, 256x256)
__global__ void prep1(const float* __restrict__ W_upd, const float* __restrict__ W_proj,
                      float* __restrict__ M1) {
    int i = blockIdx.x;   // output row n
    int j = threadIdx.x;  // output col c
    const float* wrow = W_upd + i * 512 + 256;
    float acc = 0.f;
    for (int k = 0; k < 256; ++k) acc += wrow[k] * W_proj[k * 256 + j];
    M1[i * 256 + j] = acc;
}

// Wbig[n][0:256] = bf16(W1[n][:]); Wbig[n][256:384] = bf16((M1 @ W_a2o)[n][:])
// v1[n] = M1[n][:] . b_a2o ; v2[n] = W2[n][:] . b_proj + b_upd[n]
__global__ void prep2(const float* __restrict__ W_upd, const float* __restrict__ W_a2o,
                      const float* __restrict__ b_a2o, const float* __restrict__ b_proj,
                      const float* __restrict__ b_upd, const float* __restrict__ M1,
                      unsigned short* __restrict__ Wbig, float* __restrict__ v1,
                      float* __restrict__ v2) {
    int i = blockIdx.x;   // n
    int j = threadIdx.x;  // 0..127
    const float* m1row = M1 + i * 256;
    float acc = 0.f;
    for (int k = 0; k < 256; ++k) acc += m1row[k] * W_a2o[k * 128 + j];
    Wbig[i * K_TOT + 256 + j] = (unsigned short)f2bf(acc);
    Wbig[i * K_TOT + j]       = (unsigned short)f2bf(W_upd[i * 512 + j]);
    Wbig[i * K_TOT + 128 + j] = (unsigned short)f2bf(W_upd[i * 512 + 128 + j]);

    __shared__ float r1[128], r2[128];
    r1[j] = m1row[j] * b_a2o[j] + m1row[j + 128] * b_a2o[j + 128];
    r2[j] = W_upd[i * 512 + 256 + j] * b_proj[j] +
            W_upd[i * 512 + 256 + 128 + j] * b_proj[j + 128];
    __syncthreads();
    for (int s = 64; s > 0; s >>= 1) {
        if (j < s) { r1[j] += r1[j + s]; r2[j] += r2[j + s]; }
        __syncthreads();
    }
    if (j == 0) { v1[i] = r1[0]; v2[i] = r2[0] + b_upd[i]; }
}

// ---------------- edge counting sort ----------------
__global__ void hist_kernel(const int* __restrict__ ei, int* __restrict__ count) {
    int e = blockIdx.x * blockDim.x + threadIdx.x;
    if (e < E_NUM) atomicAdd(&count[ei[e]], 1);
}

// ---- parallel 3-phase exclusive scan of count[80000] -> start[80001] + cursor ----
__global__ void scan_partial(const int* __restrict__ count, int* __restrict__ blockSums) {
    __shared__ int sh[256];
    int t = threadIdx.x;
    int base = blockIdx.x * SCAN_CHUNK + t * 4;
    int s = 0;
    if (base + 3 < M_ROWS) {
        int4 v = *reinterpret_cast<const int4*>(count + base);
        s = v.x + v.y + v.z + v.w;
    } else {
        for (int i = 0; i < 4; ++i) if (base + i < M_ROWS) s += count[base + i];
    }
    sh[t] = s;
    __syncthreads();
    for (int off = 128; off > 0; off >>= 1) {
        if (t < off) sh[t] += sh[t + off];
        __syncthreads();
    }
    if (t == 0) blockSums[blockIdx.x] = sh[0];
}

__global__ void scan_sums(const int* __restrict__ blockSums, int* __restrict__ blockOffsets) {
    __shared__ int sh[128];
    int t = threadIdx.x;
    int v = (t < SCAN_NBLK) ? blockSums[t] : 0;
    sh[t] = v;
    __syncthreads();
    for (int off = 1; off < 128; off <<= 1) {
        int u = (t >= off) ? sh[t - off] : 0;
        __syncthreads();
        sh[t] += u;
        __syncthreads();
    }
    if (t < SCAN_NBLK) blockOffsets[t] = sh[t] - v;  // exclusive
}

__global__ void scan_final(const int* __restrict__ count, const int* __restrict__ blockOffsets,
                           int* __restrict__ start, int* __restrict__ cursor) {
    __shared__ int sh[256];
    int t = threadIdx.x;
    int base = blockIdx.x * SCAN_CHUNK + t * 4;
    int c0 = 0, c1 = 0, c2 = 0, c3 = 0;
    if (base + 3 < M_ROWS) {
        int4 v = *reinterpret_cast<const int4*>(count + base);
        c0 = v.x; c1 = v.y; c2 = v.z; c3 = v.w;
    } else {
        if (base + 0 < M_ROWS) c0 = count[base + 0];
        if (base + 1 < M_ROWS) c1 = count[base + 1];
        if (base + 2 < M_ROWS) c2 = count[base + 2];
        if (base + 3 < M_ROWS) c3 = count[base + 3];
    }
    int s = c0 + c1 + c2 + c3;
    sh[t] = s;
    __syncthreads();
    for (int off = 1; off < 256; off <<= 1) {
        int u = (t >= off) ? sh[t - off] : 0;
        __syncthreads();
        sh[t] += u;
        __syncthreads();
    }
    int run = blockOffsets[blockIdx.x] + sh[t] - s;  // exclusive prefix for this thread
    if (base + 0 < M_ROWS) { start[base + 0] = run; cursor[base + 0] = run; run += c0; }
    if (base + 1 < M_ROWS) { start[base + 1] = run; cursor[base + 1] = run; run += c1; }
    if (base + 2 < M_ROWS) { start[base + 2] = run; cursor[base + 2] = run; run += c2; }
    if (base + 3 < M_ROWS) { start[base + 3] = run; cursor[base + 3] = run; run += c3; }
    if (blockIdx.x == 0 && t == 0) start[M_ROWS] = E_NUM;
}

__global__ void scatter_kernel(const int* __restrict__ ei, const float* __restrict__ ew,
                               int* __restrict__ cursor, int* __restrict__ s_attr,
                               float* __restrict__ s_w) {
    int e = blockIdx.x * blockDim.x + threadIdx.x;
    if (e < E_NUM) {
        int o = ei[e];
        int pos = atomicAdd(&cursor[o], 1);
        s_attr[pos] = ei[E_NUM + e];
        s_w[pos] = ew[e];
    }
}

// ---------------- aggregation: one wave per object, no atomics ----------------
__global__ void __launch_bounds__(256) agg_kernel(const float* __restrict__ attrs,
        const int* __restrict__ start, const int* __restrict__ s_attr,
        const float* __restrict__ s_w, float* __restrict__ nrm, float* __restrict__ s_out) {
    int wave = (int)((blockIdx.x * blockDim.x + threadIdx.x) >> 6);
    int lane = threadIdx.x & 63;
    if (wave >= M_ROWS) return;
    int beg = start[wave], end = start[wave + 1];
    float a0 = 0.f, a1 = 0.f, ws = 0.f;
    for (int j = beg; j < end; ++j) {
        int a = s_attr[j];
        float w = s_w[j];
        float2 v = *reinterpret_cast<const float2*>(attrs + (size_t)a * ATTR_DIM + lane * 2);
        a0 += w * v.x; a1 += w * v.y; ws += w;
    }
    float inv = 1.f / fmaxf(ws, 1e-6f);
    float2 o; o.x = a0 * inv; o.y = a1 * inv;
    *reinterpret_cast<float2*>(nrm + (size_t)wave * ATTR_DIM + lane * 2) = o;
    if (lane == 0) s_out[wave] = ws * inv;
}

// ---------------- fused output GEMM: out = relu(X[80000,384] @ Wbig.T + s*v1 + v2) ----------------
// block = 256 thr = 4 waves; wave computes 32 rows x 256 cols; block = 128 rows. grid = 625.
__global__ void __launch_bounds__(256, 2) gemm_out(
    const float* __restrict__ obj, const float* __restrict__ nrm,
    const unsigned short* __restrict__ Wbig, const float* __restrict__ v1,
    const float* __restrict__ v2, const float* __restrict__ s_arr,
    float* __restrict__ out) {
    __shared__ unsigned short Bs[256][40];  // 32 used + 8 pad (bank spread), rows 16B-aligned

    int tid = threadIdx.x;
    int w = tid >> 6, lane = tid & 63;
    int l15 = lane & 15, quad = lane >> 4;
    int m_base = blockIdx.x * 128 + w * 32;

    f32x4 acc[2][16];
#pragma unroll
    for (int a = 0; a < 2; ++a)
#pragma unroll
        for (int b = 0; b < 16; ++b) acc[a][b] = (f32x4){0.f, 0.f, 0.f, 0.f};

    for (int kt = 0; kt < 12; ++kt) {
        int k0 = kt * 32;
        __syncthreads();
        {   // stage B chunk: thread t loads Wbig[t][k0..k0+32)
            const int4* src = reinterpret_cast<const int4*>(Wbig + tid * K_TOT + k0);
            int4 q0 = src[0], q1 = src[1], q2 = src[2], q3 = src[3];
            int4* dst = reinterpret_cast<int4*>(&Bs[tid][0]);
            dst[0] = q0; dst[1] = q1; dst[2] = q2; dst[3] = q3;
        }
        __syncthreads();

        bf16x8 af[2];
#pragma unroll
        for (int mt = 0; mt < 2; ++mt) {
            int m = m_base + mt * 16 + l15;
            const float* p;
            if (k0 < 256) p = obj + (size_t)m * 256 + k0 + quad * 8;
            else          p = nrm + (size_t)m * 128 + (k0 - 256) + quad * 8;
            float4 x0 = *reinterpret_cast<const float4*>(p);
            float4 x1 = *reinterpret_cast<const float4*>(p + 4);
            bf16x8 a;
            a[0] = f2bf(x0.x); a[1] = f2bf(x0.y); a[2] = f2bf(x0.z); a[3] = f2bf(x0.w);
            a[4] = f2bf(x1.x); a[5] = f2bf(x1.y); a[6] = f2bf(x1.z); a[7] = f2bf(x1.w);
            af[mt] = a;
        }
#pragma unroll
        for (int nt = 0; nt < 16; ++nt) {
            bf16x8 bf_ = *reinterpret_cast<const bf16x8*>(&Bs[nt * 16 + l15][quad * 8]);
            acc[0][nt] = __builtin_amdgcn_mfma_f32_16x16x32_bf16(af[0], bf_, acc[0][nt], 0, 0, 0);
            acc[1][nt] = __builtin_amdgcn_mfma_f32_16x16x32_bf16(af[1], bf_, acc[1][nt], 0, 0, 0);
        }
    }

    float v1v[16], v2v[16];
#pragma unroll
    for (int nt = 0; nt < 16; ++nt) {
        v1v[nt] = v1[nt * 16 + l15];
        v2v[nt] = v2[nt * 16 + l15];
    }
#pragma unroll
    for (int mt = 0; mt < 2; ++mt) {
#pragma unroll
        for (int r = 0; r < 4; ++r) {
            int m = m_base + mt * 16 + quad * 4 + r;
            float sv = s_arr[m];
            float* orow = out + (size_t)m * 256;
#pragma unroll
            for (int nt = 0; nt < 16; ++nt) {
                float val = acc[mt][nt][r] + sv * v1v[nt] + v2v[nt];
                orow[nt * 16 + l15] = fmaxf(val, 0.f);
            }
        }
    }
}

// ---------------- launch ----------------
extern "C" void kernel_launch(void* const* d_in, const int* in_sizes, int n_in,
                              void* d_out, int out_size, void* d_ws, size_t ws_size,
                              hipStream_t stream) {
    const float* obj    = (const float*)d_in[0];
    const float* attrs  = (const float*)d_in[1];
    const int*   ei     = (const int*)d_in[2];
    const float* ew     = (const float*)d_in[3];
    const float* W_a2o  = (const float*)d_in[4];
    const float* b_a2o  = (const float*)d_in[5];
    const float* W_proj = (const float*)d_in[6];
    const float* b_proj = (const float*)d_in[7];
    const float* W_upd  = (const float*)d_in[8];
    const float* b_upd  = (const float*)d_in[9];
    float* out = (float*)d_out;
    char* ws = (char*)d_ws;

    // workspace layout (bytes)
    float* nrm            = (float*)(ws);                       // 80000*128*4 = 40,960,000
    float* s_arr          = (float*)(ws + 40960000);            // 320,000
    int*   count          = (int*)  (ws + 41280000);            // 320,000
    int*   start          = (int*)  (ws + 41600000);            // 320,004 (pad to 320,256)
    int*   cursor         = (int*)  (ws + 41920256);            // 320,000
    int*   s_attr         = (int*)  (ws + 42240256);            // 3,200,000
    float* s_w            = (float*)(ws + 45440256);            // 3,200,000
    float* M1             = (float*)(ws + 48640256);            // 262,144 (dead after prep2)
    unsigned short* Wbig  = (unsigned short*)(ws + 48902400);   // 196,608
    float* v1             = (float*)(ws + 49099008);            // 1,024
    float* v2             = (float*)(ws + 49100032);            // 1,024
    // scan scratch reuses M1's region (prep2 has completed before scans run)
    int* blockSums        = (int*)  (ws + 48640256);            // 316 B (pad 512)
    int* blockOffsets     = (int*)  (ws + 48640256 + 512);      // 316 B

    hipMemsetAsync(count, 0, M_ROWS * sizeof(int), stream);

    prep1<<<256, 256, 0, stream>>>(W_upd, W_proj, M1);
    prep2<<<256, 128, 0, stream>>>(W_upd, W_a2o, b_a2o, b_proj, b_upd, M1, Wbig, v1, v2);
    hist_kernel<<<(E_NUM + 255) / 256, 256, 0, stream>>>(ei, count);
    scan_partial<<<SCAN_NBLK, 256, 0, stream>>>(count, blockSums);
    scan_sums<<<1, 128, 0, stream>>>(blockSums, blockOffsets);
    scan_final<<<SCAN_NBLK, 256, 0, stream>>>(count, blockOffsets, start, cursor);
    scatter_kernel<<<(E_NUM + 255) / 256, 256, 0, stream>>>(ei, ew, cursor, s_attr, s_w);
    agg_kernel<<<M_ROWS / 4, 256, 0, stream>>>(attrs, start, s_attr, s_w, nrm, s_arr);
    gemm_out<<<M_ROWS / 128, 256, 0, stream>>>(obj, nrm, Wbig, v1, v2, s_arr, out);
}

// Round 4
// 379.540 us; speedup vs baseline: 1.4920x; 1.0349x over previous
//
#include <hip/hip_runtime.h>
#include <hip/hip_bf16.h>

// Problem constants (from reference setup_inputs)
#define BSZ      8
#define NOBJ     10000
#define NATTR    2000
#define IN_DIM   256
#define OUT_DIM  256
#define ATTR_DIM 128
#define E_NUM    800000
#define M_ROWS   (BSZ * NOBJ)    // 80000 object rows
#define K_TOT    (IN_DIM + ATTR_DIM)  // 384 fused K

#define SCAN_CHUNK 1024
#define SCAN_NBLK  ((M_ROWS + SCAN_CHUNK - 1) / SCAN_CHUNK)  // 79

typedef short bf16x8 __attribute__((ext_vector_type(8)));
typedef float f32x4  __attribute__((ext_vector_type(4)));

__device__ __forceinline__ short f2bf(float f) {
    union { float f; unsigned u; } v; v.f = f;
    unsigned r = v.u + 0x7FFFu + ((v.u >> 16) & 1u);  // RNE
    return (short)(r >> 16);
}
__device__ __forceinline__ unsigned pack_bf2(float x, float y) {
    return ((unsigned)(unsigned short)f2bf(x)) | (((unsigned)(unsigned short)f2bf(y)) << 16);
}

// ---------------- prep: fused weight precompute ----------------
// M1[n][c] = sum_k W_upd[n][256+k] * W_proj[k][c]   (W2 @ W_proj, 256x256)
__global__ void prep1(const float* __restrict__ W_upd, const float* __restrict__ W_proj,
                      float* __restrict__ M1) {
    int i = blockIdx.x;   // output row n
    int j = threadIdx.x;  // output col c
    const float* wrow = W_upd + i * 512 + 256;
    float acc = 0.f;
    for (int k = 0; k < 256; ++k) acc += wrow[k] * W_proj[k * 256 + j];
    M1[i * 256 + j] = acc;
}

// Wbig[n][0:256] = bf16(W1[n][:]); Wbig[n][256:384] = bf16((M1 @ W_a2o)[n][:])
// v1[n] = M1[n][:] . b_a2o ; v2[n] = W2[n][:] . b_proj + b_upd[n]
__global__ void prep2(const float* __restrict__ W_upd, const float* __restrict__ W_a2o,
                      const float* __restrict__ b_a2o, const float* __restrict__ b_proj,
                      const float* __restrict__ b_upd, const float* __restrict__ M1,
                      unsigned short* __restrict__ Wbig, float* __restrict__ v1,
                      float* __restrict__ v2) {
    int i = blockIdx.x;   // n
    int j = threadIdx.x;  // 0..127
    const float* m1row = M1 + i * 256;
    float acc = 0.f;
    for (int k = 0; k < 256; ++k) acc += m1row[k] * W_a2o[k * 128 + j];
    Wbig[i * K_TOT + 256 + j] = (unsigned short)f2bf(acc);
    Wbig[i * K_TOT + j]       = (unsigned short)f2bf(W_upd[i * 512 + j]);
    Wbig[i * K_TOT + 128 + j] = (unsigned short)f2bf(W_upd[i * 512 + 128 + j]);

    __shared__ float r1[128], r2[128];
    r1[j] = m1row[j] * b_a2o[j] + m1row[j + 128] * b_a2o[j + 128];
    r2[j] = W_upd[i * 512 + 256 + j] * b_proj[j] +
            W_upd[i * 512 + 256 + 128 + j] * b_proj[j + 128];
    __syncthreads();
    for (int s = 64; s > 0; s >>= 1) {
        if (j < s) { r1[j] += r1[j + s]; r2[j] += r2[j + s]; }
        __syncthreads();
    }
    if (j == 0) { v1[i] = r1[0]; v2[i] = r2[0] + b_upd[i]; }
}

// ---------------- attrs fp32 -> bf16 (4.1 MB table: fits per-XCD L2) ----------------
__global__ void conv_attrs(const float* __restrict__ attrs, unsigned int* __restrict__ attrs_bf) {
    int i = blockIdx.x * blockDim.x + threadIdx.x;  // pair index, 16000*64 = 1,024,000
    float2 v = *reinterpret_cast<const float2*>(attrs + (size_t)i * 2);
    attrs_bf[i] = pack_bf2(v.x, v.y);
}

// ---------------- edge counting sort ----------------
__global__ void hist_kernel(const int* __restrict__ ei, int* __restrict__ count) {
    int e = blockIdx.x * blockDim.x + threadIdx.x;
    if (e < E_NUM) atomicAdd(&count[ei[e]], 1);
}

// ---- parallel 3-phase exclusive scan of count[80000] -> start[80001] + cursor ----
__global__ void scan_partial(const int* __restrict__ count, int* __restrict__ blockSums) {
    __shared__ int sh[256];
    int t = threadIdx.x;
    int base = blockIdx.x * SCAN_CHUNK + t * 4;
    int s = 0;
    if (base + 3 < M_ROWS) {
        int4 v = *reinterpret_cast<const int4*>(count + base);
        s = v.x + v.y + v.z + v.w;
    } else {
        for (int i = 0; i < 4; ++i) if (base + i < M_ROWS) s += count[base + i];
    }
    sh[t] = s;
    __syncthreads();
    for (int off = 128; off > 0; off >>= 1) {
        if (t < off) sh[t] += sh[t + off];
        __syncthreads();
    }
    if (t == 0) blockSums[blockIdx.x] = sh[0];
}

__global__ void scan_sums(const int* __restrict__ blockSums, int* __restrict__ blockOffsets) {
    __shared__ int sh[128];
    int t = threadIdx.x;
    int v = (t < SCAN_NBLK) ? blockSums[t] : 0;
    sh[t] = v;
    __syncthreads();
    for (int off = 1; off < 128; off <<= 1) {
        int u = (t >= off) ? sh[t - off] : 0;
        __syncthreads();
        sh[t] += u;
        __syncthreads();
    }
    if (t < SCAN_NBLK) blockOffsets[t] = sh[t] - v;  // exclusive
}

__global__ void scan_final(const int* __restrict__ count, const int* __restrict__ blockOffsets,
                           int* __restrict__ start, int* __restrict__ cursor) {
    __shared__ int sh[256];
    int t = threadIdx.x;
    int base = blockIdx.x * SCAN_CHUNK + t * 4;
    int c0 = 0, c1 = 0, c2 = 0, c3 = 0;
    if (base + 3 < M_ROWS) {
        int4 v = *reinterpret_cast<const int4*>(count + base);
        c0 = v.x; c1 = v.y; c2 = v.z; c3 = v.w;
    } else {
        if (base + 0 < M_ROWS) c0 = count[base + 0];
        if (base + 1 < M_ROWS) c1 = count[base + 1];
        if (base + 2 < M_ROWS) c2 = count[base + 2];
        if (base + 3 < M_ROWS) c3 = count[base + 3];
    }
    int s = c0 + c1 + c2 + c3;
    sh[t] = s;
    __syncthreads();
    for (int off = 1; off < 256; off <<= 1) {
        int u = (t >= off) ? sh[t - off] : 0;
        __syncthreads();
        sh[t] += u;
        __syncthreads();
    }
    int run = blockOffsets[blockIdx.x] + sh[t] - s;  // exclusive prefix for this thread
    if (base + 0 < M_ROWS) { start[base + 0] = run; cursor[base + 0] = run; run += c0; }
    if (base + 1 < M_ROWS) { start[base + 1] = run; cursor[base + 1] = run; run += c1; }
    if (base + 2 < M_ROWS) { start[base + 2] = run; cursor[base + 2] = run; run += c2; }
    if (base + 3 < M_ROWS) { start[base + 3] = run; cursor[base + 3] = run; run += c3; }
    if (blockIdx.x == 0 && t == 0) start[M_ROWS] = E_NUM;
}

__global__ void scatter_kernel(const int* __restrict__ ei, const float* __restrict__ ew,
                               int* __restrict__ cursor, int2* __restrict__ s_edge) {
    int e = blockIdx.x * blockDim.x + threadIdx.x;
    if (e < E_NUM) {
        int o = ei[e];
        int pos = atomicAdd(&cursor[o], 1);
        s_edge[pos] = make_int2(ei[E_NUM + e], __float_as_int(ew[e]));
    }
}

// ---------------- aggregation: one wave per object, no atomics ----------------
__global__ void __launch_bounds__(256) agg_kernel(const unsigned int* __restrict__ attrs_bf,
        const int* __restrict__ start, const int2* __restrict__ s_edge,
        unsigned int* __restrict__ nrm, float* __restrict__ s_out) {
    int wave = (int)((blockIdx.x * blockDim.x + threadIdx.x) >> 6);
    int lane = threadIdx.x & 63;
    if (wave >= M_ROWS) return;
    int beg = start[wave], end = start[wave + 1];
    float a0 = 0.f, a1 = 0.f, ws = 0.f;
    int2 er;
    if (beg < end) er = s_edge[beg];
    for (int j = beg; j < end; ++j) {
        int2 nx;
        if (j + 1 < end) nx = s_edge[j + 1];   // prefetch next record (breaks dep chain)
        float w = __int_as_float(er.y);
        unsigned int u = attrs_bf[er.x * 64 + lane];
        a0 += w * __uint_as_float(u << 16);
        a1 += w * __uint_as_float(u & 0xFFFF0000u);
        ws += w;
        er = nx;
    }
    float inv = 1.f / fmaxf(ws, 1e-6f);
    nrm[wave * 64 + lane] = pack_bf2(a0 * inv, a1 * inv);
    if (lane == 0) s_out[wave] = ws * inv;
}

// ---------------- fused output GEMM: out = relu(X[80000,384] @ Wbig.T + s*v1 + v2) ----------------
// block = 256 thr = 4 waves; wave computes 32 rows x 256 cols; block = 128 rows. grid = 625.
__global__ void __launch_bounds__(256, 2) gemm_out(
    const float* __restrict__ obj, const unsigned short* __restrict__ nrm,
    const unsigned short* __restrict__ Wbig, const float* __restrict__ v1,
    const float* __restrict__ v2, const float* __restrict__ s_arr,
    float* __restrict__ out) {
    __shared__ unsigned short Bs[256][40];  // 32 used + 8 pad (bank spread), rows 16B-aligned

    int tid = threadIdx.x;
    int w = tid >> 6, lane = tid & 63;
    int l15 = lane & 15, quad = lane >> 4;
    int m_base = blockIdx.x * 128 + w * 32;

    f32x4 acc[2][16];
#pragma unroll
    for (int a = 0; a < 2; ++a)
#pragma unroll
        for (int b = 0; b < 16; ++b) acc[a][b] = (f32x4){0.f, 0.f, 0.f, 0.f};

    for (int kt = 0; kt < 12; ++kt) {
        int k0 = kt * 32;
        __syncthreads();
        {   // stage B chunk: thread t loads Wbig[t][k0..k0+32)
            const int4* src = reinterpret_cast<const int4*>(Wbig + tid * K_TOT + k0);
            int4 q0 = src[0], q1 = src[1], q2 = src[2], q3 = src[3];
            int4* dst = reinterpret_cast<int4*>(&Bs[tid][0]);
            dst[0] = q0; dst[1] = q1; dst[2] = q2; dst[3] = q3;
        }
        __syncthreads();

        bf16x8 af[2];
#pragma unroll
        for (int mt = 0; mt < 2; ++mt) {
            int m = m_base + mt * 16 + l15;
            if (k0 < 256) {
                const float* p = obj + (size_t)m * 256 + k0 + quad * 8;
                float4 x0 = *reinterpret_cast<const float4*>(p);
                float4 x1 = *reinterpret_cast<const float4*>(p + 4);
                bf16x8 a;
                a[0] = f2bf(x0.x); a[1] = f2bf(x0.y); a[2] = f2bf(x0.z); a[3] = f2bf(x0.w);
                a[4] = f2bf(x1.x); a[5] = f2bf(x1.y); a[6] = f2bf(x1.z); a[7] = f2bf(x1.w);
                af[mt] = a;
            } else {
                af[mt] = *reinterpret_cast<const bf16x8*>(nrm + (size_t)m * 128 + (k0 - 256) + quad * 8);
            }
        }
#pragma unroll
        for (int nt = 0; nt < 16; ++nt) {
            bf16x8 bf_ = *reinterpret_cast<const bf16x8*>(&Bs[nt * 16 + l15][quad * 8]);
            acc[0][nt] = __builtin_amdgcn_mfma_f32_16x16x32_bf16(af[0], bf_, acc[0][nt], 0, 0, 0);
            acc[1][nt] = __builtin_amdgcn_mfma_f32_16x16x32_bf16(af[1], bf_, acc[1][nt], 0, 0, 0);
        }
    }

    float v1v[16], v2v[16];
#pragma unroll
    for (int nt = 0; nt < 16; ++nt) {
        v1v[nt] = v1[nt * 16 + l15];
        v2v[nt] = v2[nt * 16 + l15];
    }
#pragma unroll
    for (int mt = 0; mt < 2; ++mt) {
#pragma unroll
        for (int r = 0; r < 4; ++r) {
            int m = m_base + mt * 16 + quad * 4 + r;
            float sv = s_arr[m];
            float* orow = out + (size_t)m * 256;
#pragma unroll
            for (int nt = 0; nt < 16; ++nt) {
                float val = acc[mt][nt][r] + sv * v1v[nt] + v2v[nt];
                orow[nt * 16 + l15] = fmaxf(val, 0.f);
            }
        }
    }
}

// ---------------- launch ----------------
extern "C" void kernel_launch(void* const* d_in, const int* in_sizes, int n_in,
                              void* d_out, int out_size, void* d_ws, size_t ws_size,
                              hipStream_t stream) {
    const float* obj    = (const float*)d_in[0];
    const float* attrs  = (const float*)d_in[1];
    const int*   ei     = (const int*)d_in[2];
    const float* ew     = (const float*)d_in[3];
    const float* W_a2o  = (const float*)d_in[4];
    const float* b_a2o  = (const float*)d_in[5];
    const float* W_proj = (const float*)d_in[6];
    const float* b_proj = (const float*)d_in[7];
    const float* W_upd  = (const float*)d_in[8];
    const float* b_upd  = (const float*)d_in[9];
    float* out = (float*)d_out;
    char* ws = (char*)d_ws;

    // workspace layout (bytes)
    unsigned int* nrm      = (unsigned int*)(ws);                // 80000*128*2 = 20,480,000 (bf16)
    float* s_arr           = (float*)(ws + 20480000);            // 320,000
    int*   count           = (int*)  (ws + 20800000);            // 320,000
    int*   start           = (int*)  (ws + 21120000);            // 320,256 (incl pad)
    int*   cursor          = (int*)  (ws + 21440256);            // 320,000
    int2*  s_edge          = (int2*) (ws + 21760256);            // 6,400,000
    unsigned int* attrs_bf = (unsigned int*)(ws + 28160256);     // 4,096,000
    float* M1              = (float*)(ws + 32256256);            // 262,144 (dead after prep2)
    unsigned short* Wbig   = (unsigned short*)(ws + 32518400);   // 196,608
    float* v1              = (float*)(ws + 32715008);            // 1,024
    float* v2              = (float*)(ws + 32716032);            // 1,024
    // scan scratch reuses M1 region (prep2 completes before the scans run)
    int* blockSums         = (int*)  (ws + 32256256);
    int* blockOffsets      = (int*)  (ws + 32256256 + 512);

    (void)hipMemsetAsync(count, 0, M_ROWS * sizeof(int), stream);

    prep1<<<256, 256, 0, stream>>>(W_upd, W_proj, M1);
    prep2<<<256, 128, 0, stream>>>(W_upd, W_a2o, b_a2o, b_proj, b_upd, M1, Wbig, v1, v2);
    conv_attrs<<<(BSZ * NATTR * 64) / 256, 256, 0, stream>>>(attrs, attrs_bf);
    hist_kernel<<<(E_NUM + 255) / 256, 256, 0, stream>>>(ei, count);
    scan_partial<<<SCAN_NBLK, 256, 0, stream>>>(count, blockSums);
    scan_sums<<<1, 128, 0, stream>>>(blockSums, blockOffsets);
    scan_final<<<SCAN_NBLK, 256, 0, stream>>>(count, blockOffsets, start, cursor);
    scatter_kernel<<<(E_NUM + 255) / 256, 256, 0, stream>>>(ei, ew, cursor, s_edge);
    agg_kernel<<<M_ROWS / 4, 256, 0, stream>>>(attrs_bf, start, s_edge, nrm, s_arr);
    gemm_out<<<M_ROWS / 128, 256, 0, stream>>>(obj, (const unsigned short*)nrm, Wbig, v1, v2, s_arr, out);
}

// Round 5
// 353.537 us; speedup vs baseline: 1.6017x; 1.0736x over previous
//
#include <hip/hip_runtime.h>
#include <hip/hip_bf16.h>

// Problem constants (from reference setup_inputs)
#define BSZ      8
#define NOBJ     10000
#define NATTR    2000
#define IN_DIM   256
#define OUT_DIM  256
#define ATTR_DIM 128
#define E_NUM    800000
#define M_ROWS   (BSZ * NOBJ)    // 80000 object rows
#define K_TOT    (IN_DIM + ATTR_DIM)  // 384 fused K

#define SCAN_CHUNK 1024
#define SCAN_NBLK  ((M_ROWS + SCAN_CHUNK - 1) / SCAN_CHUNK)  // 79

typedef short bf16x8 __attribute__((ext_vector_type(8)));
typedef float f32x4  __attribute__((ext_vector_type(4)));

__device__ __forceinline__ short f2bf(float f) {
    union { float f; unsigned u; } v; v.f = f;
    unsigned r = v.u + 0x7FFFu + ((v.u >> 16) & 1u);  // RNE
    return (short)(r >> 16);
}
__device__ __forceinline__ unsigned pack_bf2(float x, float y) {
    return ((unsigned)(unsigned short)f2bf(x)) | (((unsigned)(unsigned short)f2bf(y)) << 16);
}

// ---------------- prep: fused weight precompute ----------------
// M1[n][c] = sum_k W_upd[n][256+k] * W_proj[k][c]   (W2 @ W_proj, 256x256)
__global__ void prep1(const float* __restrict__ W_upd, const float* __restrict__ W_proj,
                      float* __restrict__ M1) {
    int i = blockIdx.x;   // output row n
    int j = threadIdx.x;  // output col c
    const float* wrow = W_upd + i * 512 + 256;
    float acc = 0.f;
    for (int k = 0; k < 256; ++k) acc += wrow[k] * W_proj[k * 256 + j];
    M1[i * 256 + j] = acc;
}

// Wbig[n][0:256] = bf16(W1[n][:]); Wbig[n][256:384] = bf16((M1 @ W_a2o)[n][:])
// v1[n] = M1[n][:] . b_a2o ; v2[n] = W2[n][:] . b_proj + b_upd[n]
__global__ void prep2(const float* __restrict__ W_upd, const float* __restrict__ W_a2o,
                      const float* __restrict__ b_a2o, const float* __restrict__ b_proj,
                      const float* __restrict__ b_upd, const float* __restrict__ M1,
                      unsigned short* __restrict__ Wbig, float* __restrict__ v1,
                      float* __restrict__ v2) {
    int i = blockIdx.x;   // n
    int j = threadIdx.x;  // 0..127
    const float* m1row = M1 + i * 256;
    float acc = 0.f;
    for (int k = 0; k < 256; ++k) acc += m1row[k] * W_a2o[k * 128 + j];
    Wbig[i * K_TOT + 256 + j] = (unsigned short)f2bf(acc);
    Wbig[i * K_TOT + j]       = (unsigned short)f2bf(W_upd[i * 512 + j]);
    Wbig[i * K_TOT + 128 + j] = (unsigned short)f2bf(W_upd[i * 512 + 128 + j]);

    __shared__ float r1[128], r2[128];
    r1[j] = m1row[j] * b_a2o[j] + m1row[j + 128] * b_a2o[j + 128];
    r2[j] = W_upd[i * 512 + 256 + j] * b_proj[j] +
            W_upd[i * 512 + 256 + 128 + j] * b_proj[j + 128];
    __syncthreads();
    for (int s = 64; s > 0; s >>= 1) {
        if (j < s) { r1[j] += r1[j + s]; r2[j] += r2[j + s]; }
        __syncthreads();
    }
    if (j == 0) { v1[i] = r1[0]; v2[i] = r2[0] + b_upd[i]; }
}

// ---------------- attrs fp32 -> bf16 (4.1 MB table: fits per-XCD L2) ----------------
__global__ void conv_attrs(const float* __restrict__ attrs, unsigned int* __restrict__ attrs_bf) {
    int i = blockIdx.x * blockDim.x + threadIdx.x;  // pair index, 16000*64 = 1,024,000
    float2 v = *reinterpret_cast<const float2*>(attrs + (size_t)i * 2);
    attrs_bf[i] = pack_bf2(v.x, v.y);
}

// ---------------- edge counting sort ----------------
__global__ void hist_kernel(const int* __restrict__ ei, int* __restrict__ count) {
    int e = blockIdx.x * blockDim.x + threadIdx.x;
    if (e < E_NUM) atomicAdd(&count[ei[e]], 1);
}

// ---- parallel 3-phase exclusive scan of count[80000] -> start[80001] + cursor ----
__global__ void scan_partial(const int* __restrict__ count, int* __restrict__ blockSums) {
    __shared__ int sh[256];
    int t = threadIdx.x;
    int base = blockIdx.x * SCAN_CHUNK + t * 4;
    int s = 0;
    if (base + 3 < M_ROWS) {
        int4 v = *reinterpret_cast<const int4*>(count + base);
        s = v.x + v.y + v.z + v.w;
    } else {
        for (int i = 0; i < 4; ++i) if (base + i < M_ROWS) s += count[base + i];
    }
    sh[t] = s;
    __syncthreads();
    for (int off = 128; off > 0; off >>= 1) {
        if (t < off) sh[t] += sh[t + off];
        __syncthreads();
    }
    if (t == 0) blockSums[blockIdx.x] = sh[0];
}

__global__ void scan_sums(const int* __restrict__ blockSums, int* __restrict__ blockOffsets) {
    __shared__ int sh[128];
    int t = threadIdx.x;
    int v = (t < SCAN_NBLK) ? blockSums[t] : 0;
    sh[t] = v;
    __syncthreads();
    for (int off = 1; off < 128; off <<= 1) {
        int u = (t >= off) ? sh[t - off] : 0;
        __syncthreads();
        sh[t] += u;
        __syncthreads();
    }
    if (t < SCAN_NBLK) blockOffsets[t] = sh[t] - v;  // exclusive
}

__global__ void scan_final(const int* __restrict__ count, const int* __restrict__ blockOffsets,
                           int* __restrict__ start, int* __restrict__ cursor) {
    __shared__ int sh[256];
    int t = threadIdx.x;
    int base = blockIdx.x * SCAN_CHUNK + t * 4;
    int c0 = 0, c1 = 0, c2 = 0, c3 = 0;
    if (base + 3 < M_ROWS) {
        int4 v = *reinterpret_cast<const int4*>(count + base);
        c0 = v.x; c1 = v.y; c2 = v.z; c3 = v.w;
    } else {
        if (base + 0 < M_ROWS) c0 = count[base + 0];
        if (base + 1 < M_ROWS) c1 = count[base + 1];
        if (base + 2 < M_ROWS) c2 = count[base + 2];
        if (base + 3 < M_ROWS) c3 = count[base + 3];
    }
    int s = c0 + c1 + c2 + c3;
    sh[t] = s;
    __syncthreads();
    for (int off = 1; off < 256; off <<= 1) {
        int u = (t >= off) ? sh[t - off] : 0;
        __syncthreads();
        sh[t] += u;
        __syncthreads();
    }
    int run = blockOffsets[blockIdx.x] + sh[t] - s;  // exclusive prefix for this thread
    if (base + 0 < M_ROWS) { start[base + 0] = run; cursor[base + 0] = run; run += c0; }
    if (base + 1 < M_ROWS) { start[base + 1] = run; cursor[base + 1] = run; run += c1; }
    if (base + 2 < M_ROWS) { start[base + 2] = run; cursor[base + 2] = run; run += c2; }
    if (base + 3 < M_ROWS) { start[base + 3] = run; cursor[base + 3] = run; run += c3; }
    if (blockIdx.x == 0 && t == 0) start[M_ROWS] = E_NUM;
}

__global__ void scatter_kernel(const int* __restrict__ ei, const float* __restrict__ ew,
                               int* __restrict__ cursor, int2* __restrict__ s_edge) {
    int e = blockIdx.x * blockDim.x + threadIdx.x;
    if (e < E_NUM) {
        int o = ei[e];
        int pos = atomicAdd(&cursor[o], 1);
        s_edge[pos] = make_int2(ei[E_NUM + e], __float_as_int(ew[e]));
    }
}

// ---------------- aggregation: one wave per object, 8-deep pipelined gather ----------------
__global__ void __launch_bounds__(256) agg_kernel(const unsigned int* __restrict__ attrs_bf,
        const int* __restrict__ start, const int2* __restrict__ s_edge,
        unsigned int* __restrict__ nrm, float* __restrict__ s_out) {
    int wave = (int)((blockIdx.x * blockDim.x + threadIdx.x) >> 6);
    int lane = threadIdx.x & 63;
    if (wave >= M_ROWS) return;
    int beg = start[wave], end = start[wave + 1];
    float a0 = 0.f, a1 = 0.f, ws = 0.f;
    if (beg < end) {
        int last = end - 1;
        int2 e[8];
#pragma unroll
        for (int k = 0; k < 8; ++k) e[k] = s_edge[min(beg + k, last)];
        for (int j = beg; j < end; j += 8) {
            unsigned u[8];
            float w[8];
            // issue 8 independent attr gathers (current group)
#pragma unroll
            for (int k = 0; k < 8; ++k) {
                u[k] = attrs_bf[e[k].x * 64 + lane];
                w[k] = (j + k < end) ? __int_as_float(e[k].y) : 0.f;  // mask OOB lanes
            }
            // prefetch next group's edge records while gathers are in flight
            int jn = j + 8;
            if (jn < end) {
#pragma unroll
                for (int k = 0; k < 8; ++k) e[k] = s_edge[min(jn + k, last)];
            }
            // accumulate (same j-ascending order as before: bit-identical)
#pragma unroll
            for (int k = 0; k < 8; ++k) {
                a0 += w[k] * __uint_as_float(u[k] << 16);
                a1 += w[k] * __uint_as_float(u[k] & 0xFFFF0000u);
                ws += w[k];
            }
        }
    }
    float inv = 1.f / fmaxf(ws, 1e-6f);
    nrm[wave * 64 + lane] = pack_bf2(a0 * inv, a1 * inv);
    if (lane == 0) s_out[wave] = ws * inv;
}

// ---------------- fused output GEMM: out = relu(X[80000,384] @ Wbig.T + s*v1 + v2) ----------------
// block = 256 thr = 4 waves; wave computes 32 rows x 256 cols; block = 128 rows. grid = 625.
__global__ void __launch_bounds__(256, 2) gemm_out(
    const float* __restrict__ obj, const unsigned short* __restrict__ nrm,
    const unsigned short* __restrict__ Wbig, const float* __restrict__ v1,
    const float* __restrict__ v2, const float* __restrict__ s_arr,
    float* __restrict__ out) {
    __shared__ unsigned short Bs[256][40];  // 32 used + 8 pad (bank spread), rows 16B-aligned

    int tid = threadIdx.x;
    int w = tid >> 6, lane = tid & 63;
    int l15 = lane & 15, quad = lane >> 4;
    int m_base = blockIdx.x * 128 + w * 32;

    f32x4 acc[2][16];
#pragma unroll
    for (int a = 0; a < 2; ++a)
#pragma unroll
        for (int b = 0; b < 16; ++b) acc[a][b] = (f32x4){0.f, 0.f, 0.f, 0.f};

    for (int kt = 0; kt < 12; ++kt) {
        int k0 = kt * 32;
        __syncthreads();
        {   // stage B chunk: thread t loads Wbig[t][k0..k0+32)
            const int4* src = reinterpret_cast<const int4*>(Wbig + tid * K_TOT + k0);
            int4 q0 = src[0], q1 = src[1], q2 = src[2], q3 = src[3];
            int4* dst = reinterpret_cast<int4*>(&Bs[tid][0]);
            dst[0] = q0; dst[1] = q1; dst[2] = q2; dst[3] = q3;
        }
        __syncthreads();

        bf16x8 af[2];
#pragma unroll
        for (int mt = 0; mt < 2; ++mt) {
            int m = m_base + mt * 16 + l15;
            if (k0 < 256) {
                const float* p = obj + (size_t)m * 256 + k0 + quad * 8;
                float4 x0 = *reinterpret_cast<const float4*>(p);
                float4 x1 = *reinterpret_cast<const float4*>(p + 4);
                bf16x8 a;
                a[0] = f2bf(x0.x); a[1] = f2bf(x0.y); a[2] = f2bf(x0.z); a[3] = f2bf(x0.w);
                a[4] = f2bf(x1.x); a[5] = f2bf(x1.y); a[6] = f2bf(x1.z); a[7] = f2bf(x1.w);
                af[mt] = a;
            } else {
                af[mt] = *reinterpret_cast<const bf16x8*>(nrm + (size_t)m * 128 + (k0 - 256) + quad * 8);
            }
        }
#pragma unroll
        for (int nt = 0; nt < 16; ++nt) {
            bf16x8 bf_ = *reinterpret_cast<const bf16x8*>(&Bs[nt * 16 + l15][quad * 8]);
            acc[0][nt] = __builtin_amdgcn_mfma_f32_16x16x32_bf16(af[0], bf_, acc[0][nt], 0, 0, 0);
            acc[1][nt] = __builtin_amdgcn_mfma_f32_16x16x32_bf16(af[1], bf_, acc[1][nt], 0, 0, 0);
        }
    }

    float v1v[16], v2v[16];
#pragma unroll
    for (int nt = 0; nt < 16; ++nt) {
        v1v[nt] = v1[nt * 16 + l15];
        v2v[nt] = v2[nt * 16 + l15];
    }
#pragma unroll
    for (int mt = 0; mt < 2; ++mt) {
#pragma unroll
        for (int r = 0; r < 4; ++r) {
            int m = m_base + mt * 16 + quad * 4 + r;
            float sv = s_arr[m];
            float* orow = out + (size_t)m * 256;
#pragma unroll
            for (int nt = 0; nt < 16; ++nt) {
                float val = acc[mt][nt][r] + sv * v1v[nt] + v2v[nt];
                orow[nt * 16 + l15] = fmaxf(val, 0.f);
            }
        }
    }
}

// ---------------- launch ----------------
extern "C" void kernel_launch(void* const* d_in, const int* in_sizes, int n_in,
                              void* d_out, int out_size, void* d_ws, size_t ws_size,
                              hipStream_t stream) {
    const float* obj    = (const float*)d_in[0];
    const float* attrs  = (const float*)d_in[1];
    const int*   ei     = (const int*)d_in[2];
    const float* ew     = (const float*)d_in[3];
    const float* W_a2o  = (const float*)d_in[4];
    const float* b_a2o  = (const float*)d_in[5];
    const float* W_proj = (const float*)d_in[6];
    const float* b_proj = (const float*)d_in[7];
    const float* W_upd  = (const float*)d_in[8];
    const float* b_upd  = (const float*)d_in[9];
    float* out = (float*)d_out;
    char* ws = (char*)d_ws;

    // workspace layout (bytes)
    unsigned int* nrm      = (unsigned int*)(ws);                // 80000*128*2 = 20,480,000 (bf16)
    float* s_arr           = (float*)(ws + 20480000);            // 320,000
    int*   count           = (int*)  (ws + 20800000);            // 320,000
    int*   start           = (int*)  (ws + 21120000);            // 320,256 (incl pad)
    int*   cursor          = (int*)  (ws + 21440256);            // 320,000
    int2*  s_edge          = (int2*) (ws + 21760256);            // 6,400,000
    unsigned int* attrs_bf = (unsigned int*)(ws + 28160256);     // 4,096,000
    float* M1              = (float*)(ws + 32256256);            // 262,144 (dead after prep2)
    unsigned short* Wbig   = (unsigned short*)(ws + 32518400);   // 196,608
    float* v1              = (float*)(ws + 32715008);            // 1,024
    float* v2              = (float*)(ws + 32716032);            // 1,024
    // scan scratch reuses M1 region (prep2 completes before the scans run)
    int* blockSums         = (int*)  (ws + 32256256);
    int* blockOffsets      = (int*)  (ws + 32256256 + 512);

    (void)hipMemsetAsync(count, 0, M_ROWS * sizeof(int), stream);

    prep1<<<256, 256, 0, stream>>>(W_upd, W_proj, M1);
    prep2<<<256, 128, 0, stream>>>(W_upd, W_a2o, b_a2o, b_proj, b_upd, M1, Wbig, v1, v2);
    conv_attrs<<<(BSZ * NATTR * 64) / 256, 256, 0, stream>>>(attrs, attrs_bf);
    hist_kernel<<<(E_NUM + 255) / 256, 256, 0, stream>>>(ei, count);
    scan_partial<<<SCAN_NBLK, 256, 0, stream>>>(count, blockSums);
    scan_sums<<<1, 128, 0, stream>>>(blockSums, blockOffsets);
    scan_final<<<SCAN_NBLK, 256, 0, stream>>>(count, blockOffsets, start, cursor);
    scatter_kernel<<<(E_NUM + 255) / 256, 256, 0, stream>>>(ei, ew, cursor, s_edge);
    agg_kernel<<<M_ROWS / 4, 256, 0, stream>>>(attrs_bf, start, s_edge, nrm, s_arr);
    gemm_out<<<M_ROWS / 128, 256, 0, stream>>>(obj, (const unsigned short*)nrm, Wbig, v1, v2, s_arr, out);
}